// Round 4
// baseline (319.771 us; speedup 1.0000x reference)
//
#include <hip/hip_runtime.h>
#include <hip/hip_bf16.h>
#include <math.h>

#define INV_T (1.0f / 0.07f)

typedef __bf16 bf16x8 __attribute__((ext_vector_type(8)));
typedef float f32x4 __attribute__((ext_vector_type(4)));

__device__ __forceinline__ void gld16(const void* g, void* l) {
    __builtin_amdgcn_global_load_lds(
        (const __attribute__((address_space(1))) unsigned int*)g,
        (__attribute__((address_space(3))) unsigned int*)l,
        16, 0, 0);
}

// ---------------- normalize + bf16 pack + positive dot + zero S/cnt --------
__global__ __launch_bounds__(256) void norm_kernel(
    const float4* __restrict__ f1, const float4* __restrict__ f2,
    ushort4* __restrict__ F, float* __restrict__ S, float* __restrict__ P,
    unsigned int* __restrict__ cnt, int B) {
    const int i = blockIdx.x;
    const int t = threadIdx.x;

    float4 x = f1[i * 256 + t];
    float4 y = f2[i * 256 + t];

    float s1 = x.x * x.x + x.y * x.y + x.z * x.z + x.w * x.w;
    float s2 = y.x * y.x + y.y * y.y + y.z * y.z + y.w * y.w;
    float dd = x.x * y.x + x.y * y.y + x.z * y.z + x.w * y.w;

    for (int o = 32; o > 0; o >>= 1) {
        s1 += __shfl_down(s1, o);
        s2 += __shfl_down(s2, o);
        dd += __shfl_down(dd, o);
    }
    __shared__ float red[4][3];
    const int wv = t >> 6, ln = t & 63;
    if (ln == 0) { red[wv][0] = s1; red[wv][1] = s2; red[wv][2] = dd; }
    __syncthreads();
    s1 = red[0][0] + red[1][0] + red[2][0] + red[3][0];
    s2 = red[0][1] + red[1][1] + red[2][1] + red[3][1];
    dd = red[0][2] + red[1][2] + red[2][2] + red[3][2];

    const float rn1 = 1.0f / fmaxf(sqrtf(s1), 1e-12f);
    const float rn2 = 1.0f / fmaxf(sqrtf(s2), 1e-12f);

    union { ushort4 u; __hip_bfloat16 h[4]; } p;
    p.h[0] = __float2bfloat16(x.x * rn1);
    p.h[1] = __float2bfloat16(x.y * rn1);
    p.h[2] = __float2bfloat16(x.z * rn1);
    p.h[3] = __float2bfloat16(x.w * rn1);
    F[(size_t)i * 256 + t] = p.u;
    p.h[0] = __float2bfloat16(y.x * rn2);
    p.h[1] = __float2bfloat16(y.y * rn2);
    p.h[2] = __float2bfloat16(y.z * rn2);
    p.h[3] = __float2bfloat16(y.w * rn2);
    F[(size_t)(B + i) * 256 + t] = p.u;

    if (t == 0) {
        P[i] = dd * rn1 * rn2;
        S[i] = 0.0f;
        S[B + i] = 0.0f;
        if (i == 0) *cnt = 0u;
    }
}

// ---------------- fused sim-GEMM + exp + row/col-sum + finalize ------------
// 128x256 block tile, strictly-upper counting (gRow<gCol credited to both
// S[gRow], S[gCol]); tiles k = tj^2+tj+ti, ti in [0,2tj+2).
// A strip (128 rows) LDS double-buffered via global_load_lds (1 barrier/iter).
// B fragments read DIRECTLY from global (L2/L3-resident F) -> no B staging,
// no B ds_reads, MFMA<->global_load interleaving with fine-grained vmcnt.
// Last block (ticket) computes the scalar loss in-kernel.
__global__ __launch_bounds__(256, 2) void sim_kernel(
    const __hip_bfloat16* __restrict__ F, float* __restrict__ S,
    const float* __restrict__ P, unsigned int* __restrict__ cnt,
    float* __restrict__ out, int N, int D, int B) {
    __shared__ __align__(16) __hip_bfloat16 As[2][128][64];  // 32 KB

    const int k = blockIdx.x;
    int tj = (int)((sqrtf(4.0f * (float)k + 1.0f) - 1.0f) * 0.5f);
    while ((tj + 1) * (tj + 2) <= k) ++tj;
    while (tj * (tj + 1) > k) --tj;
    const int ti = k - tj * (tj + 1);
    const int bRow = ti * 128;
    const int bCol = tj * 256;

    const int tid  = threadIdx.x;
    const int wave = tid >> 6;
    const int lane = tid & 63;
    const int quad = lane >> 4;
    const int l16  = lane & 15;

    const int srow   = lane >> 3;                 // 0..7
    const int ldsOff = (lane & 7) * 8;            // dest slot (elements)
    const int srcOff = ((lane & 7) ^ srow) * 8;   // swizzled source chunk

    const int waveRow = (wave >> 1) * 64;
    const int waveCol = (wave & 1) * 128;
    const int swz = l16 & 7;

    // per-lane global base for B fragments (row bCol+waveCol+l16, col quad*8)
    const __hip_bfloat16* bp = F + (size_t)(bCol + waveCol + l16) * D + quad * 8;

    f32x4 acc[4][8];
#pragma unroll
    for (int mi = 0; mi < 4; ++mi)
#pragma unroll
        for (int ni = 0; ni < 8; ++ni)
            acc[mi][ni] = (f32x4){0.0f, 0.0f, 0.0f, 0.0f};

    // prologue: stage A tile 0 into buf 0
#pragma unroll
    for (int p = 0; p < 4; ++p) {
        const int rowT = (p * 4 + wave) * 8 + srow;
        gld16(&F[(size_t)(bRow + rowT) * D + srcOff], &As[0][rowT][ldsOff]);
    }
    __syncthreads();

    const int NIT = D / 64;  // 16
    for (int it = 0; it < NIT; ++it) {
        const int kb = it * 64;
        // prefetch next A tile into other buffer (drained at end-of-iter barrier)
        if (it + 1 < NIT) {
#pragma unroll
            for (int p = 0; p < 4; ++p) {
                const int rowT = (p * 4 + wave) * 8 + srow;
                gld16(&F[(size_t)(bRow + rowT) * D + kb + 64 + srcOff],
                      &As[(it + 1) & 1][rowT][ldsOff]);
            }
        }
        const int buf = it & 1;
#pragma unroll
        for (int ks = 0; ks < 2; ++ks) {
            const int slot = ((ks * 4 + quad) ^ swz) * 8;
            bf16x8 bfr[8];
#pragma unroll
            for (int ni = 0; ni < 8; ++ni)
                bfr[ni] = *(const bf16x8*)(bp + (size_t)ni * 16 * D + kb + ks * 32);
#pragma unroll
            for (int mi = 0; mi < 4; ++mi) {
                const bf16x8 af = *(const bf16x8*)&As[buf][waveRow + mi * 16 + l16][slot];
#pragma unroll
                for (int ni = 0; ni < 8; ++ni)
                    acc[mi][ni] = __builtin_amdgcn_mfma_f32_16x16x32_bf16(
                        af, bfr[ni], acc[mi][ni], 0, 0, 0);
            }
        }
        __syncthreads();
    }

    // ---- epilogue: e = (gRow<gCol) ? exp((c-1)/T) : 0; row+col sums ----
#pragma unroll
    for (int mi = 0; mi < 4; ++mi)
#pragma unroll
        for (int ni = 0; ni < 8; ++ni)
#pragma unroll
            for (int r = 0; r < 4; ++r) {
                const int gRow = bRow + waveRow + mi * 16 + quad * 4 + r;
                const int gCol = bCol + waveCol + ni * 16 + l16;
                acc[mi][ni][r] = (gRow < gCol)
                    ? __expf((acc[mi][ni][r] - 1.0f) * INV_T) : 0.0f;
            }

#pragma unroll
    for (int mi = 0; mi < 4; ++mi)
#pragma unroll
        for (int r = 0; r < 4; ++r) {
            const int gRow = bRow + waveRow + mi * 16 + quad * 4 + r;
            float v = 0.0f;
#pragma unroll
            for (int ni = 0; ni < 8; ++ni) v += acc[mi][ni][r];
            v += __shfl_xor(v, 1);
            v += __shfl_xor(v, 2);
            v += __shfl_xor(v, 4);
            v += __shfl_xor(v, 8);
            if (l16 == 0) atomicAdd(&S[gRow], v);
        }

#pragma unroll
    for (int ni = 0; ni < 8; ++ni) {
        float cv = 0.0f;
#pragma unroll
        for (int mi = 0; mi < 4; ++mi)
#pragma unroll
            for (int r = 0; r < 4; ++r) cv += acc[mi][ni][r];
        cv += __shfl_xor(cv, 16);
        cv += __shfl_xor(cv, 32);
        if (quad == 0) atomicAdd(&S[bCol + waveCol + ni * 16 + l16], cv);
    }

    // ---- last-block finalize ----
    __threadfence();
    __shared__ unsigned int ticket;
    if (tid == 0) ticket = atomicAdd(cnt, 1u);
    __syncthreads();
    if (ticket == (unsigned int)(gridDim.x - 1)) {
        __threadfence();
        volatile const float* Sv = S;
        float s = 0.0f;
        for (int i = tid; i < N; i += 256) s += __logf(Sv[i]);
        float pp = 0.0f;
        for (int i = tid; i < B; i += 256) pp += P[i];
        for (int o = 32; o > 0; o >>= 1) {
            s += __shfl_down(s, o);
            pp += __shfl_down(pp, o);
        }
        __shared__ float red[4][2];
        if ((tid & 63) == 0) { red[tid >> 6][0] = s; red[tid >> 6][1] = pp; }
        __syncthreads();
        if (tid == 0) {
            const float sl = red[0][0] + red[1][0] + red[2][0] + red[3][0];
            const float ps = red[0][1] + red[1][1] + red[2][1] + red[3][1];
            out[0] = INV_T + sl / (float)N - ps * (2.0f * INV_T / (float)N);
        }
    }
}

extern "C" void kernel_launch(void* const* d_in, const int* in_sizes, int n_in,
                              void* d_out, int out_size, void* d_ws, size_t ws_size,
                              hipStream_t stream) {
    const int D = 1024;
    const int B = in_sizes[0] / D;   // 4096
    const int N = 2 * B;             // 8192
    const int M2 = N / 256;          // 32 col-tiles
    const int ntiles = M2 * M2 + M2; // 1056

    const float* f1 = (const float*)d_in[0];
    const float* f2 = (const float*)d_in[1];

    __hip_bfloat16* F = (__hip_bfloat16*)d_ws;  // N*D bf16 = 16 MB
    float* S = (float*)((char*)d_ws + (size_t)N * D * sizeof(__hip_bfloat16));
    float* P = S + N;                 // B floats
    unsigned int* cnt = (unsigned int*)(P + B);

    norm_kernel<<<dim3(B), dim3(256), 0, stream>>>(
        (const float4*)f1, (const float4*)f2, (ushort4*)F, S, P, cnt, B);
    sim_kernel<<<dim3(ntiles), dim3(256), 0, stream>>>(
        F, S, P, cnt, (float*)d_out, N, D, B);
}

// Round 5
// 221.548 us; speedup vs baseline: 1.4433x; 1.4433x over previous
//
#include <hip/hip_runtime.h>
#include <hip/hip_bf16.h>
#include <math.h>

#define INV_T (1.0f / 0.07f)

typedef float f32x4 __attribute__((ext_vector_type(4)));

__device__ __forceinline__ void gld16(const void* g, void* l) {
    __builtin_amdgcn_global_load_lds(
        (const __attribute__((address_space(1))) unsigned int*)g,
        (__attribute__((address_space(3))) unsigned int*)l,
        16, 0, 0);
}

// ---------------- normalize + fp8 pack + positive dot + zero S/cnt ---------
// one block per pair-row i. F is N x D fp8(e4m3), row-major.
__global__ __launch_bounds__(256) void norm_kernel(
    const float4* __restrict__ f1, const float4* __restrict__ f2,
    unsigned int* __restrict__ F, float* __restrict__ S, float* __restrict__ P,
    unsigned int* __restrict__ cnt, int B) {
    const int i = blockIdx.x;
    const int t = threadIdx.x;

    float4 x = f1[(size_t)i * 256 + t];
    float4 y = f2[(size_t)i * 256 + t];

    float s1 = x.x * x.x + x.y * x.y + x.z * x.z + x.w * x.w;
    float s2 = y.x * y.x + y.y * y.y + y.z * y.z + y.w * y.w;
    float dd = x.x * y.x + x.y * y.y + x.z * y.z + x.w * y.w;

    for (int o = 32; o > 0; o >>= 1) {
        s1 += __shfl_down(s1, o);
        s2 += __shfl_down(s2, o);
        dd += __shfl_down(dd, o);
    }
    __shared__ float red[4][3];
    const int wv = t >> 6, ln = t & 63;
    if (ln == 0) { red[wv][0] = s1; red[wv][1] = s2; red[wv][2] = dd; }
    __syncthreads();
    s1 = red[0][0] + red[1][0] + red[2][0] + red[3][0];
    s2 = red[0][1] + red[1][1] + red[2][1] + red[3][1];
    dd = red[0][2] + red[1][2] + red[2][2] + red[3][2];

    const float rn1 = 1.0f / fmaxf(sqrtf(s1), 1e-12f);
    const float rn2 = 1.0f / fmaxf(sqrtf(s2), 1e-12f);

    // pack 4 fp8 (e4m3, OCP) per thread per row via v_cvt_pk_fp8_f32
    unsigned int w1 = __builtin_amdgcn_cvt_pk_fp8_f32(x.x * rn1, x.y * rn1, 0, 0);
    w1 = __builtin_amdgcn_cvt_pk_fp8_f32(x.z * rn1, x.w * rn1, w1, 1);
    F[(size_t)i * 256 + t] = w1;
    unsigned int w2 = __builtin_amdgcn_cvt_pk_fp8_f32(y.x * rn2, y.y * rn2, 0, 0);
    w2 = __builtin_amdgcn_cvt_pk_fp8_f32(y.z * rn2, y.w * rn2, w2, 1);
    F[(size_t)(B + i) * 256 + t] = w2;

    if (t == 0) {
        P[i] = dd * rn1 * rn2;
        S[i] = 0.0f;
        S[B + i] = 0.0f;
        if (i == 0) *cnt = 0u;
    }
}

// ---------------- fused fp8 sim-GEMM + exp + row/col-sum + finalize --------
// 128x256 block tile, BK=128 fp8. Strictly-upper counting (gRow<gCol), each
// exp credited to S[gRow] and S[gCol]. Tiles k = tj^2+tj+ti, ti in [0,2tj+2),
// 1056 total; grid = 1024 blocks, blocks 0..31 take tiles {b, b+32} (they
// dispatch first), blocks >=32 take tile b+32 -> ~2.06-round makespan.
// XOR-swizzled LDS at 16B granularity: slot s at row r holds chunk s^(r&7).
__global__ __launch_bounds__(256, 2) void sim_kernel(
    const unsigned char* __restrict__ F, float* __restrict__ S,
    const float* __restrict__ P, unsigned int* __restrict__ cnt,
    float* __restrict__ out, int N, int D, int B) {
    __shared__ __align__(16) unsigned char As[128][128];  // 16 KB
    __shared__ __align__(16) unsigned char Bs[256][128];  // 32 KB

    const int tid  = threadIdx.x;
    const int wave = tid >> 6;
    const int lane = tid & 63;
    const int quad = lane >> 4;
    const int l16  = lane & 15;

    // staging map: 64 lanes cover 8 rows x 8 slots of 16B
    const int srow   = lane >> 3;                  // row-in-8
    const int ldsOff = (lane & 7) * 16;            // dest slot bytes
    const int srcOff = ((lane & 7) ^ srow) * 16;   // swizzled source bytes

    const int waveRow = (wave >> 1) * 64;
    const int waveCol = (wave & 1) * 128;

    const int ntile = (blockIdx.x < 32) ? 2 : 1;
    for (int tt = 0; tt < ntile; ++tt) {
        const int k = (tt == 0) ? (int)(blockIdx.x + 32 * (blockIdx.x >= 32))
                                : (int)(blockIdx.x + 32);
        int tj = (int)((sqrtf(4.0f * (float)k + 1.0f) - 1.0f) * 0.5f);
        while ((tj + 1) * (tj + 2) <= k) ++tj;
        while (tj * (tj + 1) > k) --tj;
        const int ti = k - tj * (tj + 1);
        const int bRow = ti * 128;
        const int bCol = tj * 256;

        f32x4 acc[4][8];
#pragma unroll
        for (int mi = 0; mi < 4; ++mi)
#pragma unroll
            for (int ni = 0; ni < 8; ++ni)
                acc[mi][ni] = (f32x4){0.0f, 0.0f, 0.0f, 0.0f};

        for (int kb = 0; kb < D; kb += 128) {
#pragma unroll
            for (int p = 0; p < 4; ++p) {
                const int rowT = (p * 4 + wave) * 8 + srow;  // 0..127
                gld16(&F[(size_t)(bRow + rowT) * D + kb + srcOff], &As[rowT][ldsOff]);
            }
#pragma unroll
            for (int p = 0; p < 8; ++p) {
                const int rowT = (p * 4 + wave) * 8 + srow;  // 0..255
                gld16(&F[(size_t)(bCol + rowT) * D + kb + srcOff], &Bs[rowT][ldsOff]);
            }
            __syncthreads();

#pragma unroll
            for (int ks = 0; ks < 4; ++ks) {
                const int g = ks * 4 + quad;      // 8B-chunk index 0..15
                const int G = g >> 1;             // 16B slot pre-swizzle
                const int sub = (g & 1) * 8;
                long bfr[8];
#pragma unroll
                for (int ni = 0; ni < 8; ++ni) {
                    const int r = waveCol + ni * 16 + l16;
                    bfr[ni] = *(const long*)&Bs[r][(G ^ (r & 7)) * 16 + sub];
                }
#pragma unroll
                for (int mi = 0; mi < 4; ++mi) {
                    const int r = waveRow + mi * 16 + l16;
                    const long af = *(const long*)&As[r][(G ^ (r & 7)) * 16 + sub];
#pragma unroll
                    for (int ni = 0; ni < 8; ++ni)
                        acc[mi][ni] = __builtin_amdgcn_mfma_f32_16x16x32_fp8_fp8(
                            af, bfr[ni], acc[mi][ni], 0, 0, 0);
                }
            }
            __syncthreads();
        }

        // ---- epilogue: e = (gRow<gCol) ? exp((c-1)/T) : 0; row+col sums ----
#pragma unroll
        for (int mi = 0; mi < 4; ++mi)
#pragma unroll
            for (int ni = 0; ni < 8; ++ni)
#pragma unroll
                for (int r = 0; r < 4; ++r) {
                    const int gRow = bRow + waveRow + mi * 16 + quad * 4 + r;
                    const int gCol = bCol + waveCol + ni * 16 + l16;
                    acc[mi][ni][r] = (gRow < gCol)
                        ? __expf((acc[mi][ni][r] - 1.0f) * INV_T) : 0.0f;
                }

#pragma unroll
        for (int mi = 0; mi < 4; ++mi)
#pragma unroll
            for (int r = 0; r < 4; ++r) {
                const int gRow = bRow + waveRow + mi * 16 + quad * 4 + r;
                float v = 0.0f;
#pragma unroll
                for (int ni = 0; ni < 8; ++ni) v += acc[mi][ni][r];
                v += __shfl_xor(v, 1);
                v += __shfl_xor(v, 2);
                v += __shfl_xor(v, 4);
                v += __shfl_xor(v, 8);
                if (l16 == 0) atomicAdd(&S[gRow], v);
            }

#pragma unroll
        for (int ni = 0; ni < 8; ++ni) {
            float cv = 0.0f;
#pragma unroll
            for (int mi = 0; mi < 4; ++mi)
#pragma unroll
                for (int r = 0; r < 4; ++r) cv += acc[mi][ni][r];
            cv += __shfl_xor(cv, 16);
            cv += __shfl_xor(cv, 32);
            if (quad == 0) atomicAdd(&S[bCol + waveCol + ni * 16 + l16], cv);
        }
        if (tt + 1 < ntile) __syncthreads();
    }

    // ---- last-block finalize ----
    __threadfence();
    __shared__ unsigned int ticket;
    if (tid == 0) ticket = atomicAdd(cnt, 1u);
    __syncthreads();
    if (ticket == (unsigned int)(gridDim.x - 1)) {
        __threadfence();
        volatile const float* Sv = S;
        float s = 0.0f;
        for (int i = tid; i < N; i += 256) s += __logf(Sv[i]);
        float pp = 0.0f;
        for (int i = tid; i < B; i += 256) pp += P[i];
        for (int o = 32; o > 0; o >>= 1) {
            s += __shfl_down(s, o);
            pp += __shfl_down(pp, o);
        }
        __shared__ float red[4][2];
        if ((tid & 63) == 0) { red[tid >> 6][0] = s; red[tid >> 6][1] = pp; }
        __syncthreads();
        if (tid == 0) {
            const float sl = red[0][0] + red[1][0] + red[2][0] + red[3][0];
            const float ps = red[0][1] + red[1][1] + red[2][1] + red[3][1];
            out[0] = INV_T + sl / (float)N - ps * (2.0f * INV_T / (float)N);
        }
    }
}

extern "C" void kernel_launch(void* const* d_in, const int* in_sizes, int n_in,
                              void* d_out, int out_size, void* d_ws, size_t ws_size,
                              hipStream_t stream) {
    const int D = 1024;
    const int B = in_sizes[0] / D;   // 4096
    const int N = 2 * B;             // 8192

    const float* f1 = (const float*)d_in[0];
    const float* f2 = (const float*)d_in[1];

    unsigned char* F = (unsigned char*)d_ws;              // N*D fp8 = 8 MB
    float* S = (float*)(F + (size_t)N * D);
    float* P = S + N;                                      // B floats
    unsigned int* cnt = (unsigned int*)(P + B);

    norm_kernel<<<dim3(B), dim3(256), 0, stream>>>(
        (const float4*)f1, (const float4*)f2, (unsigned int*)F, S, P, cnt, B);
    sim_kernel<<<dim3(1024), dim3(256), 0, stream>>>(
        F, S, P, cnt, (float*)d_out, N, D, B);
}

// Round 6
// 192.837 us; speedup vs baseline: 1.6582x; 1.1489x over previous
//
#include <hip/hip_runtime.h>
#include <hip/hip_bf16.h>
#include <math.h>

#define INV_T (1.0f / 0.07f)

typedef float f32x4 __attribute__((ext_vector_type(4)));
typedef long lx2 __attribute__((ext_vector_type(2)));   // 16B = two fp8 MFMA operands

__device__ __forceinline__ void gld16(const void* g, void* l) {
    __builtin_amdgcn_global_load_lds(
        (const __attribute__((address_space(1))) unsigned int*)g,
        (__attribute__((address_space(3))) unsigned int*)l,
        16, 0, 0);
}

// ---------------- normalize + fp8 pack + positive dot + zero S/cnt ---------
__global__ __launch_bounds__(256) void norm_kernel(
    const float4* __restrict__ f1, const float4* __restrict__ f2,
    unsigned int* __restrict__ F, float* __restrict__ S, float* __restrict__ P,
    unsigned int* __restrict__ cnt, int B) {
    const int i = blockIdx.x;
    const int t = threadIdx.x;

    float4 x = f1[(size_t)i * 256 + t];
    float4 y = f2[(size_t)i * 256 + t];

    float s1 = x.x * x.x + x.y * x.y + x.z * x.z + x.w * x.w;
    float s2 = y.x * y.x + y.y * y.y + y.z * y.z + y.w * y.w;
    float dd = x.x * y.x + x.y * y.y + x.z * y.z + x.w * y.w;

    for (int o = 32; o > 0; o >>= 1) {
        s1 += __shfl_down(s1, o);
        s2 += __shfl_down(s2, o);
        dd += __shfl_down(dd, o);
    }
    __shared__ float red[4][3];
    const int wv = t >> 6, ln = t & 63;
    if (ln == 0) { red[wv][0] = s1; red[wv][1] = s2; red[wv][2] = dd; }
    __syncthreads();
    s1 = red[0][0] + red[1][0] + red[2][0] + red[3][0];
    s2 = red[0][1] + red[1][1] + red[2][1] + red[3][1];
    dd = red[0][2] + red[1][2] + red[2][2] + red[3][2];

    const float rn1 = 1.0f / fmaxf(sqrtf(s1), 1e-12f);
    const float rn2 = 1.0f / fmaxf(sqrtf(s2), 1e-12f);

    unsigned int w1 = __builtin_amdgcn_cvt_pk_fp8_f32(x.x * rn1, x.y * rn1, 0, 0);
    w1 = __builtin_amdgcn_cvt_pk_fp8_f32(x.z * rn1, x.w * rn1, w1, 1);
    F[(size_t)i * 256 + t] = w1;
    unsigned int w2 = __builtin_amdgcn_cvt_pk_fp8_f32(y.x * rn2, y.y * rn2, 0, 0);
    w2 = __builtin_amdgcn_cvt_pk_fp8_f32(y.z * rn2, y.w * rn2, w2, 1);
    F[(size_t)(B + i) * 256 + t] = w2;

    if (t == 0) {
        P[i] = dd * rn1 * rn2;
        S[i] = 0.0f;
        S[B + i] = 0.0f;
        if (i == 0) { cnt[0] = 0u; cnt[1] = 0u; }
    }
}

// ---------------- fused fp8 sim-GEMM + exp + row/col-sum + finalize --------
// Persistent 512-block grid; tiles pulled via atomic work-stealing (cnt[1]).
// 128x256 tile, BK=128 fp8. Strictly-upper counting (gRow<gCol), exp credited
// to S[gRow] and S[gCol]. K-permuted fragment map: MFMA step s (quad q) uses
// chunk q*4+s, so each lane's 4 steps = 32 contiguous bytes -> 2x ds_read_b128
// per row per K-iter. XOR-swizzle at 16B: logical slot h stored at h^(r&7).
__global__ __launch_bounds__(256, 2) void sim_kernel(
    const unsigned char* __restrict__ F, float* __restrict__ S,
    const float* __restrict__ P, unsigned int* __restrict__ cnt,
    float* __restrict__ out, int N, int D, int B, int NT) {
    __shared__ __align__(16) unsigned char As[128][128];  // 16 KB
    __shared__ __align__(16) unsigned char Bs[256][128];  // 32 KB
    __shared__ int kShared;

    const int tid  = threadIdx.x;
    const int wave = tid >> 6;
    const int lane = tid & 63;
    const int quad = lane >> 4;
    const int l16  = lane & 15;

    const int srow   = lane >> 3;                  // row-in-8 for staging
    const int ldsOff = (lane & 7) * 16;            // dest slot bytes
    const int srcOff = ((lane & 7) ^ srow) * 16;   // swizzled source chunk

    const int waveRow = (wave >> 1) * 64;
    const int waveCol = (wave & 1) * 128;

    while (true) {
        if (tid == 0) kShared = (int)atomicAdd(&cnt[1], 1u);
        __syncthreads();
        const int k = kShared;
        if (k >= NT) break;

        int tj = (int)((sqrtf(4.0f * (float)k + 1.0f) - 1.0f) * 0.5f);
        while ((tj + 1) * (tj + 2) <= k) ++tj;
        while (tj * (tj + 1) > k) --tj;
        const int ti = k - tj * (tj + 1);
        const int bRow = ti * 128;
        const int bCol = tj * 256;

        f32x4 acc[4][8];
#pragma unroll
        for (int mi = 0; mi < 4; ++mi)
#pragma unroll
            for (int ni = 0; ni < 8; ++ni)
                acc[mi][ni] = (f32x4){0.0f, 0.0f, 0.0f, 0.0f};

        for (int kb = 0; kb < D; kb += 128) {
#pragma unroll
            for (int p = 0; p < 4; ++p) {
                const int rowT = (p * 4 + wave) * 8 + srow;  // 0..127
                gld16(&F[(size_t)(bRow + rowT) * D + kb + srcOff], &As[rowT][ldsOff]);
            }
#pragma unroll
            for (int p = 0; p < 8; ++p) {
                const int rowT = (p * 4 + wave) * 8 + srow;  // 0..255
                gld16(&F[(size_t)(bCol + rowT) * D + kb + srcOff], &Bs[rowT][ldsOff]);
            }
            __syncthreads();

#pragma unroll
            for (int hf = 0; hf < 2; ++hf) {
                // logical 16B slot for this quad/half; phys = h ^ (row&7)
                lx2 bfr[8];
#pragma unroll
                for (int ni = 0; ni < 8; ++ni) {
                    const int r = waveCol + ni * 16 + l16;
                    bfr[ni] = *(const lx2*)&Bs[r][(((quad << 1) | hf) ^ (r & 7)) * 16];
                }
                lx2 afr[4];
#pragma unroll
                for (int mi = 0; mi < 4; ++mi) {
                    const int r = waveRow + mi * 16 + l16;
                    afr[mi] = *(const lx2*)&As[r][(((quad << 1) | hf) ^ (r & 7)) * 16];
                }
#pragma unroll
                for (int mi = 0; mi < 4; ++mi)
#pragma unroll
                    for (int ni = 0; ni < 8; ++ni) {
                        acc[mi][ni] = __builtin_amdgcn_mfma_f32_16x16x32_fp8_fp8(
                            afr[mi].x, bfr[ni].x, acc[mi][ni], 0, 0, 0);
                        acc[mi][ni] = __builtin_amdgcn_mfma_f32_16x16x32_fp8_fp8(
                            afr[mi].y, bfr[ni].y, acc[mi][ni], 0, 0, 0);
                    }
            }
            __syncthreads();
        }

        // ---- epilogue: e = (gRow<gCol) ? exp((c-1)/T) : 0; row+col sums ----
#pragma unroll
        for (int mi = 0; mi < 4; ++mi)
#pragma unroll
            for (int ni = 0; ni < 8; ++ni)
#pragma unroll
                for (int r = 0; r < 4; ++r) {
                    const int gRow = bRow + waveRow + mi * 16 + quad * 4 + r;
                    const int gCol = bCol + waveCol + ni * 16 + l16;
                    acc[mi][ni][r] = (gRow < gCol)
                        ? __expf((acc[mi][ni][r] - 1.0f) * INV_T) : 0.0f;
                }

#pragma unroll
        for (int mi = 0; mi < 4; ++mi)
#pragma unroll
            for (int r = 0; r < 4; ++r) {
                const int gRow = bRow + waveRow + mi * 16 + quad * 4 + r;
                float v = 0.0f;
#pragma unroll
                for (int ni = 0; ni < 8; ++ni) v += acc[mi][ni][r];
                v += __shfl_xor(v, 1);
                v += __shfl_xor(v, 2);
                v += __shfl_xor(v, 4);
                v += __shfl_xor(v, 8);
                if (l16 == 0) atomicAdd(&S[gRow], v);
            }

#pragma unroll
        for (int ni = 0; ni < 8; ++ni) {
            float cv = 0.0f;
#pragma unroll
            for (int mi = 0; mi < 4; ++mi)
#pragma unroll
                for (int r = 0; r < 4; ++r) cv += acc[mi][ni][r];
            cv += __shfl_xor(cv, 16);
            cv += __shfl_xor(cv, 32);
            if (quad == 0) atomicAdd(&S[bCol + waveCol + ni * 16 + l16], cv);
        }
    }

    // ---- last-block finalize ----
    __threadfence();
    __shared__ unsigned int ticket;
    if (tid == 0) ticket = atomicAdd(&cnt[0], 1u);
    __syncthreads();
    if (ticket == (unsigned int)(gridDim.x - 1)) {
        __threadfence();
        volatile const float* Sv = S;
        float s = 0.0f;
        for (int i = tid; i < N; i += 256) s += __logf(Sv[i]);
        float pp = 0.0f;
        for (int i = tid; i < B; i += 256) pp += P[i];
        for (int o = 32; o > 0; o >>= 1) {
            s += __shfl_down(s, o);
            pp += __shfl_down(pp, o);
        }
        __shared__ float red2[4][2];
        if ((tid & 63) == 0) { red2[tid >> 6][0] = s; red2[tid >> 6][1] = pp; }
        __syncthreads();
        if (tid == 0) {
            const float sl = red2[0][0] + red2[1][0] + red2[2][0] + red2[3][0];
            const float ps = red2[0][1] + red2[1][1] + red2[2][1] + red2[3][1];
            out[0] = INV_T + sl / (float)N - ps * (2.0f * INV_T / (float)N);
        }
    }
}

extern "C" void kernel_launch(void* const* d_in, const int* in_sizes, int n_in,
                              void* d_out, int out_size, void* d_ws, size_t ws_size,
                              hipStream_t stream) {
    const int D = 1024;
    const int B = in_sizes[0] / D;   // 4096
    const int N = 2 * B;             // 8192
    const int M2 = N / 256;          // 32
    const int NT = M2 * M2 + M2;     // 1056 tiles

    const float* f1 = (const float*)d_in[0];
    const float* f2 = (const float*)d_in[1];

    unsigned char* F = (unsigned char*)d_ws;              // N*D fp8 = 8 MB
    float* S = (float*)(F + (size_t)N * D);
    float* P = S + N;                                      // B floats
    unsigned int* cnt = (unsigned int*)(P + B);            // [ticket, work]

    norm_kernel<<<dim3(B), dim3(256), 0, stream>>>(
        (const float4*)f1, (const float4*)f2, (unsigned int*)F, S, P, cnt, B);
    sim_kernel<<<dim3(512), dim3(256), 0, stream>>>(
        F, S, P, cnt, (float*)d_out, N, D, B, NT);
}